// Round 13
// baseline (1600.598 us; speedup 1.0000x reference)
//
#include <hip/hip_runtime.h>
#include <math.h>

typedef __attribute__((ext_vector_type(8))) short short8v;   // 8 bf16 = 4 VGPRs
typedef __attribute__((ext_vector_type(4))) float float4v;   // MFMA acc

constexpr int Bsz = 8, Tn = 16, CINc = 6, Fc = 64, NCc = 10;
constexpr int PIX = 8192;                 // 8*32*32 pixels per timestep
constexpr float BN_EPS = 1e-3f;

// weight-fragment region offsets (in ushort elements)
constexpr int FR_L0X = 0;                 // 2 chunks  (K=54 padded to 64)
constexpr int FR_L0H = 16384;             // 18 chunks (K=576)
constexpr int FR_L1X = 163840;            // 18 chunks
constexpr int FR_L1H = 311296;            // 18 chunks
constexpr int FR_TOTAL = 458752;

__device__ __forceinline__ ushort f2bf(float f) {
    union { float f; unsigned u; } v; v.f = f;
    unsigned r = v.u + 0x7FFFu + ((v.u >> 16) & 1u);   // RNE
    return (ushort)(r >> 16);
}
__device__ __forceinline__ float bf2f(ushort u) {
    union { unsigned u; float f; } v; v.u = ((unsigned)u) << 16; return v.f;
}
__device__ __forceinline__ float hsig(float x) {
    return fminf(fmaxf(0.2f * x + 0.5f, 0.0f), 1.0f);
}

// ---------------- prep: x -> bf16 [t][pix][6] ----------------
__global__ __launch_bounds__(256) void prep_x(const float* __restrict__ in,
                                              ushort* __restrict__ xb) {
    int o = blockIdx.x * 256 + threadIdx.x;        // 16*8192*6 = 786432
    if (o >= Tn * PIX * CINc) return;
    int t = o / (PIX * CINc);
    int rem = o - t * (PIX * CINc);
    int pix = rem / CINc, c = rem - pix * CINc;
    int b = pix >> 10, p = pix & 1023;
    xb[o] = f2bf(in[((b * Tn + t) * 1024 + p) * CINc + c]);
}

// ---------------- prep: weights -> grouped B-fragment layout ----------------
__global__ __launch_bounds__(256) void prep_w(const float* __restrict__ W0x,
                                              const float* __restrict__ W0h,
                                              const float* __restrict__ W1x,
                                              const float* __restrict__ W1h,
                                              ushort* __restrict__ F) {
    int o = blockIdx.x * 256 + threadIdx.x;
    if (o >= FR_TOTAL) return;
    const float* W; int K; int base;
    if (o < FR_L0H)      { W = W0x; K = 54;  base = FR_L0X; }
    else if (o < FR_L1X) { W = W0h; K = 576; base = FR_L0H; }
    else if (o < FR_L1H) { W = W1x; K = 576; base = FR_L1X; }
    else                 { W = W1h; K = 576; base = FR_L1H; }
    int r = o - base;
    int e = r & 7, lane = (r >> 3) & 63, j = (r >> 9) & 7, nh = (r >> 12) & 1, kc = r >> 13;
    int nt = ((j >> 1) << 2) + nh * 2 + (j & 1);
    int k = kc * 32 + ((lane >> 4) * 4) + (e & 3) + 16 * (e >> 2);
    int n = nt * 16 + (lane & 15);
    F[o] = (k < K) ? f2bf(W[k * 256 + n]) : (ushort)0;
}

// ---------------- prep: fold BN1 into dense layer ----------------
__global__ __launch_bounds__(640) void prep_dense(
    const float* __restrict__ dW, const float* __restrict__ dB,
    const float* __restrict__ g, const float* __restrict__ be,
    const float* __restrict__ mn, const float* __restrict__ vr,
    float* __restrict__ dWf, float* __restrict__ dBf)
{
    __shared__ float sc[64], sh[64];
    int tid = threadIdx.x;
    if (tid < 64) {
        float s = g[tid] * rsqrtf(vr[tid] + BN_EPS);
        sc[tid] = s; sh[tid] = be[tid] - mn[tid] * s;
    }
    __syncthreads();
    if (tid < 640) { int f = tid / 10; dWf[tid] = sc[f] * dW[tid]; }
    if (tid < NCc) {
        float a = dB[tid];
        for (int f = 0; f < 64; ++f) a += sh[f] * dW[f * 10 + tid];
        dBf[tid] = a;
    }
}

// ---------------- init: out + sync counters ----------------
__global__ __launch_bounds__(256) void init_zero(float* out, unsigned* ctr) {
    int i = threadIdx.x;
    if (i < Bsz * NCc) out[i] = 0.f;
    if (i < 64) ctr[i] = 0u;
}

// ---------------- spin-wait on device-scope counter ----------------
__device__ __forceinline__ void wait_ge(unsigned* c, unsigned tgt) {
    if ((threadIdx.x & 63) == 0) {
        while (__hip_atomic_load(c, __ATOMIC_RELAXED, __HIP_MEMORY_SCOPE_AGENT) < tgt)
            __builtin_amdgcn_s_sleep(8);
    }
    __syncthreads();
}

// ---------------- persistent self-timed 3-stage pipeline ----------------
// 768 blocks cooperative (3/CU co-resident): grp0 = L0 steps, grp1 = z1 = conv(x1,W1x),
// grp2 = L1 steps. Per-step sync via agent-scope counters + release fences (wbL2).
// Cross-step tensors are 16-deep rings (write-once/read-once -> consumer cold-miss fresh).
// Cell state C lives in REGISTERS for all 16 steps.
__global__ __launch_bounds__(256, 3) void lstm_pipe(
    const ushort* __restrict__ Xb,
    const ushort* __restrict__ Bf0X, const ushort* __restrict__ Bf0H,
    const float* __restrict__ b0,
    const float* __restrict__ g0, const float* __restrict__ be0,
    const float* __restrict__ mn0, const float* __restrict__ v0,
    const ushort* __restrict__ Bf1X, const ushort* __restrict__ Bf1H,
    const float* __restrict__ b1,
    float* __restrict__ Z1, ushort* __restrict__ H0s,
    ushort* __restrict__ X1s, ushort* __restrict__ H1s,
    unsigned* ctr0, unsigned* ctr1, unsigned* ctr2)
{
    __shared__ ushort Hh[136 * 68];       // 64-ch halo: [yy*34+xx][68]
    __shared__ ushort Xh[136 * 8];        // grp0 x-halo

    const int tid = threadIdx.x;
    const int wid = tid >> 6, lane = tid & 63;
    const int wm = wid >> 1, wn = wid & 1;
    const int grp = blockIdx.x >> 8;
    const int bid = blockIdx.x & 255;
    const int bm = bid >> 1, nh = bid & 1;
    const int m0 = bm * 64;
    const int img = m0 >> 10;
    const int py0 = (m0 & 1023) >> 5;

    const int TOT = (grp == 0) ? 10 : 9;

    // lane pixel coords for the two m-frags
    const int p0x = wm * 32 + (lane & 15);
    const int p1x = p0x + 16;
    const int y0r = p0x >> 5, x0c = p0x & 31;
    const int y1r = p1x >> 5, x1c = p1x & 31;
    const int coff = (lane >> 4) << 2;            // c base (ushorts)
    const int boff = lane << 3;                   // B lane offset (ushorts)
    const int hch = (nh * 2 + wn) * 16 + (lane & 15);

    // invariants: bias, BN consts
    float bb[4] = {0.f, 0.f, 0.f, 0.f};
    if (grp != 2) {
        const float* bias = (grp == 0) ? b0 : b1;
#pragma unroll
        for (int g = 0; g < 4; ++g) bb[g] = bias[g * 64 + hch];
    }
    float binv = 0.f, bmu = 0.f, bbet = 0.f;
    if (grp == 0) {
        binv = g0[hch] * rsqrtf(v0[hch] + BN_EPS);
        bmu = mn0[hch]; bbet = be0[hch];
    }

    // cell state in registers (grp0 / grp2)
    float4v Creg[8];
#pragma unroll
    for (int a = 0; a < 8; ++a)
#pragma unroll
        for (int r = 0; r < 4; ++r) Creg[a][r] = 0.f;

    // B sub-chunk base (sub = 0/1 -> lower/upper 32 of K)
    auto bsub = [&](int q, int sub) -> const ushort* {
        if (grp == 0) {
            if (q == 0) return Bf0X + ((sub * 2 + nh) << 12);
            int tp = q - 1;
            return Bf0H + ((4 * tp + sub * 2 + nh) << 12);
        } else if (grp == 1) {
            return Bf1X + ((4 * q + sub * 2 + nh) << 12);
        } else {
            return Bf1H + ((4 * q + sub * 2 + nh) << 12);
        }
    };

    for (int s = 0; s < Tn; ++s) {
        // ---- dependency waits ----
        if (grp == 0)      { if (s) wait_ge(ctr0 + (s - 1), 256); }
        else if (grp == 1) { wait_ge(ctr0 + s, 256); }
        else               { wait_ge(ctr1 + s, 256); if (s) wait_ge(ctr2 + (s - 1), 256); }

        const ushort* __restrict__ Psrc =
            (grp == 0) ? (s ? H0s + (size_t)(s - 1) * (PIX * Fc) : nullptr)
          : (grp == 1) ? (X1s + (size_t)s * (PIX * Fc))
                       : (s ? H1s + (size_t)(s - 1) * (PIX * Fc) : nullptr);
        const ushort* __restrict__ Xt = Xb + s * PIX * CINc;
        float* __restrict__ Zp = Z1 + (((size_t)s * 128 + bm) * 2 + nh) * 8192;

        // ---- stage halo(s) ----
#pragma unroll
        for (int u = 0; u < 5; ++u) {
            int idx = tid + u * 256;
            if (idx < 1088) {
                int slot = idx >> 3, part = idx & 7;
                int yy = slot / 34, xx = slot - yy * 34;
                int gy = py0 - 1 + yy, gx = xx - 1;
                uint4 v = make_uint4(0u, 0u, 0u, 0u);
                if (Psrc && (unsigned)gy < 32u && (unsigned)gx < 32u)
                    v = *(const uint4*)(Psrc + (((img << 10) + gy * 32 + gx) << 6) + part * 8);
                ushort* d = &Hh[slot * 68 + part * 8];
                *(uint2*)(d)     = make_uint2(v.x, v.y);
                *(uint2*)(d + 4) = make_uint2(v.z, v.w);
            }
        }
        if (grp == 0) {
#pragma unroll
            for (int u = 0; u < 4; ++u) {
                int idx = tid + u * 256;
                if (idx < 816) {
                    int slot = idx / 6, c = idx - slot * 6;
                    int yy = slot / 34, xx = slot - yy * 34;
                    int gy = py0 - 1 + yy, gx = xx - 1;
                    ushort v = 0;
                    if ((unsigned)gy < 32u && (unsigned)gx < 32u)
                        v = Xt[((img << 10) + gy * 32 + gx) * 6 + c];
                    Xh[slot * 8 + c] = v;
                }
            }
        }

        // ---- acc init ----
        float4v acc[8];
        if (grp == 2) {
#pragma unroll
            for (int a = 0; a < 8; ++a)
                acc[a] = *(const float4v*)(Zp + (((wid * 8 + a) * 64 + lane) << 2));
        } else {
#pragma unroll
            for (int g = 0; g < 4; ++g)
#pragma unroll
                for (int r = 0; r < 4; ++r) { acc[g * 2 + 0][r] = bb[g]; acc[g * 2 + 1][r] = bb[g]; }
        }

        // x-path frag builder (grp0 chunk 0)
        auto xfrag = [&](int lry, int lcx, int half) -> short8v {
            union { ushort e[8]; short8v v; } r;
#pragma unroll
            for (int e = 0; e < 8; ++e) {
                int kg = half * 32 + coff + (e & 3) + 16 * (e >> 2);
                ushort val = 0;
                if (kg < 54) {
                    int tap = kg / 6, c = kg - tap * 6;
                    int dy = tap / 3 - 1, dxx = tap % 3 - 1;
                    val = Xh[((lry + dy + 1) * 34 + (lcx + dxx + 1)) * 8 + c];
                }
                r.e[e] = val;
            }
            return r.v;
        };

        // B(0) -> registers
        uint4 bc0[4], bc1[4], bn0[4], bn1[4];
        {
            const ushort* q0 = bsub(0, 0);
            const ushort* q1 = bsub(0, 1);
#pragma unroll
            for (int g = 0; g < 4; ++g) {
                const int jo = ((g * 2 + wn) * 64) << 3;
                bc0[g] = *(const uint4*)(q0 + jo + boff);
                bc1[g] = *(const uint4*)(q1 + jo + boff);
            }
        }

        __syncthreads();    // publish halos

        for (int q = 0; q < TOT; ++q) {
            if (q + 1 < TOT) {
                const ushort* q0 = bsub(q + 1, 0);
                const ushort* q1 = bsub(q + 1, 1);
#pragma unroll
                for (int g = 0; g < 4; ++g) {
                    const int jo = ((g * 2 + wn) * 64) << 3;
                    bn0[g] = *(const uint4*)(q0 + jo + boff);
                    bn1[g] = *(const uint4*)(q1 + jo + boff);
                }
            }

            union { struct { uint2 lo, hi; } u; short8v s; } a00, a10, a01, a11;
            if (grp == 0 && q == 0) {
                a00.s = xfrag(y0r, x0c, 0); a01.s = xfrag(y0r, x0c, 1);
                a10.s = xfrag(y1r, x1c, 0); a11.s = xfrag(y1r, x1c, 1);
            } else {
                const int tap = (grp == 0) ? q - 1 : q;
                const int dy = tap / 3 - 1, dxx = tap % 3 - 1;
                const ushort* h0r = &Hh[((y0r + dy + 1) * 34 + (x0c + dxx + 1)) * 68 + coff];
                const ushort* h1r = &Hh[((y1r + dy + 1) * 34 + (x1c + dxx + 1)) * 68 + coff];
                a00.u.lo = *(const uint2*)(h0r);      a00.u.hi = *(const uint2*)(h0r + 16);
                a01.u.lo = *(const uint2*)(h0r + 32); a01.u.hi = *(const uint2*)(h0r + 48);
                a10.u.lo = *(const uint2*)(h1r);      a10.u.hi = *(const uint2*)(h1r + 16);
                a11.u.lo = *(const uint2*)(h1r + 32); a11.u.hi = *(const uint2*)(h1r + 48);
            }

            union { uint4 u; short8v s; } bx;
#pragma unroll
            for (int g = 0; g < 4; ++g) {
                bx.u = bc0[g];
                acc[g * 2 + 0] = __builtin_amdgcn_mfma_f32_16x16x32_bf16(a00.s, bx.s, acc[g * 2 + 0], 0, 0, 0);
                acc[g * 2 + 1] = __builtin_amdgcn_mfma_f32_16x16x32_bf16(a10.s, bx.s, acc[g * 2 + 1], 0, 0, 0);
            }
#pragma unroll
            for (int g = 0; g < 4; ++g) {
                bx.u = bc1[g];
                acc[g * 2 + 0] = __builtin_amdgcn_mfma_f32_16x16x32_bf16(a01.s, bx.s, acc[g * 2 + 0], 0, 0, 0);
                acc[g * 2 + 1] = __builtin_amdgcn_mfma_f32_16x16x32_bf16(a11.s, bx.s, acc[g * 2 + 1], 0, 0, 0);
            }
#pragma unroll
            for (int g = 0; g < 4; ++g) { bc0[g] = bn0[g]; bc1[g] = bn1[g]; }
        }

        // ---- epilogues ----
        if (grp == 1) {
#pragma unroll
            for (int a = 0; a < 8; ++a) {
                float4 o;
                o.x = acc[a][0]; o.y = acc[a][1]; o.z = acc[a][2]; o.w = acc[a][3];
                *(float4*)(Zp + (((wid * 8 + a) * 64 + lane) << 2)) = o;
            }
        } else {
            ushort* __restrict__ Hc = (grp == 0) ? (H0s + (size_t)s * (PIX * Fc))
                                                 : (H1s + (size_t)s * (PIX * Fc));
            ushort* __restrict__ Seq = (grp == 0) ? (X1s + (size_t)s * (PIX * Fc)) : nullptr;
#pragma unroll
            for (int mf = 0; mf < 2; ++mf) {
#pragma unroll
                for (int r = 0; r < 4; ++r) {
                    const int p = m0 + wm * 32 + mf * 16 + (lane >> 4) * 4 + r;
                    const int o = p * 64 + hch;
                    float zi = acc[0 + mf][r];
                    float zf = acc[2 + mf][r];
                    float zg = acc[4 + mf][r];
                    float zo = acc[6 + mf][r];
                    float cv = hsig(zf) * Creg[0 + mf][r] + hsig(zi) * tanhf(zg);
                    Creg[0 + mf][r] = cv;
                    float h = hsig(zo) * tanhf(cv);
                    Hc[o] = f2bf(h);
                    if (Seq) Seq[o] = f2bf((h - bmu) * binv + bbet);
                }
            }
            // shift C storage: Creg[0..1] holds c for mf 0/1 (reuse acc slots 0..1 layout)
        }

        __syncthreads();    // all waves: stores complete (vmcnt0 at barrier), LDS reads done
        if (tid == 0) {
            __builtin_amdgcn_fence(__ATOMIC_RELEASE, "agent");   // wbL2 -> MALL
            unsigned* sc = (grp == 0) ? (ctr0 + s) : (grp == 1) ? (ctr1 + s) : (ctr2 + s);
            __hip_atomic_fetch_add(sc, 1, __ATOMIC_RELAXED, __HIP_MEMORY_SCOPE_AGENT);
        }
    }
}

// ---------------- pool over all t: h1 @ dWf (BN folded) -> softmax -> mean ----------------
__global__ __launch_bounds__(256) void pool_all(
    const ushort* __restrict__ H1seq, const float* __restrict__ dWf,
    const float* __restrict__ dBf, float* __restrict__ out)
{
    __shared__ float wlds[640];
    __shared__ float accs[NCc];
    const int tid = threadIdx.x;
    for (int i = tid; i < 640; i += 256) wlds[i] = dWf[i];
    if (tid < NCc) accs[tid] = 0.f;
    __syncthreads();

    const int gid = blockIdx.x * 256 + tid;   // 512 blocks x 256 = 131072
    const int b = (gid & 8191) >> 10;

    float logit[NCc];
#pragma unroll
    for (int c = 0; c < NCc; ++c) logit[c] = dBf[c];
    const ushort* hp = H1seq + (size_t)gid * Fc;
#pragma unroll
    for (int f0 = 0; f0 < 8; ++f0) {
        union { uint4 u; ushort s[8]; } hu;
        hu.u = *(const uint4*)(hp + f0 * 8);
#pragma unroll
        for (int j = 0; j < 8; ++j) {
            float v = bf2f(hu.s[j]);
            const float* w = &wlds[(f0 * 8 + j) * 10];
#pragma unroll
            for (int c = 0; c < NCc; ++c) logit[c] += v * w[c];
        }
    }
    float mx = logit[0];
#pragma unroll
    for (int c = 1; c < NCc; ++c) mx = fmaxf(mx, logit[c]);
    float p[NCc]; float ssum = 0.f;
#pragma unroll
    for (int c = 0; c < NCc; ++c) { p[c] = expf(logit[c] - mx); ssum += p[c]; }
    float invs = 1.f / ssum;

#pragma unroll
    for (int c = 0; c < NCc; ++c) {
        float v = p[c] * invs;
        v += __shfl_xor(v, 1);
        v += __shfl_xor(v, 2);
        v += __shfl_xor(v, 4);
        v += __shfl_xor(v, 8);
        v += __shfl_xor(v, 16);
        v += __shfl_xor(v, 32);
        if ((tid & 63) == 0) atomicAdd(&accs[c], v);
    }
    __syncthreads();
    if (tid < NCc)
        atomicAdd(&out[b * NCc + tid], accs[tid] * (1.0f / 16384.0f));
}

extern "C" void kernel_launch(void* const* d_in, const int* in_sizes, int n_in,
                              void* d_out, int out_size, void* d_ws, size_t ws_size,
                              hipStream_t stream) {
    const float* in    = (const float*)d_in[0];
    const float* l0Wx  = (const float*)d_in[1];
    const float* l0Wh  = (const float*)d_in[2];
    const float* l0b   = (const float*)d_in[3];
    const float* l0g   = (const float*)d_in[4];
    const float* l0be  = (const float*)d_in[5];
    const float* l0m   = (const float*)d_in[6];
    const float* l0v   = (const float*)d_in[7];
    const float* l1Wx  = (const float*)d_in[8];
    const float* l1Wh  = (const float*)d_in[9];
    const float* l1b   = (const float*)d_in[10];
    const float* l1g   = (const float*)d_in[11];
    const float* l1be  = (const float*)d_in[12];
    const float* l1m   = (const float*)d_in[13];
    const float* l1v   = (const float*)d_in[14];
    const float* dW    = (const float*)d_in[15];
    const float* dB    = (const float*)d_in[16];
    float* out = (float*)d_out;

    float* ws   = (float*)d_ws;
    float* z1   = ws;                         // 33,554,432 f (134 MB) z1 ring
    ushort* h0s = (ushort*)(z1 + 33554432);   // 16 x 524,288 us (h0 ring)
    ushort* x1s = h0s + 8388608;              // 16 x 524,288 us (BN'd L0 out ring)
    ushort* h1s = x1s + 8388608;              // 16 x 524,288 us (L1 h ring / pool input)
    ushort* xb  = h1s + 8388608;              // 786,432 us
    ushort* wf  = xb + 786432;                // 458,752 us
    float* dWf  = (float*)(wf + 458752);      // 640 f
    float* dBf  = dWf + 640;                  // 10 f
    unsigned* ctr = (unsigned*)(dBf + 10);    // 64 u32: ctr0[16], ctr1[16], ctr2[16]

    unsigned* ctr0 = ctr;
    unsigned* ctr1 = ctr + 16;
    unsigned* ctr2 = ctr + 32;

    prep_x<<<3072, 256, 0, stream>>>(in, xb);
    prep_w<<<1792, 256, 0, stream>>>(l0Wx, l0Wh, l1Wx, l1Wh, wf);
    prep_dense<<<1, 640, 0, stream>>>(dW, dB, l1g, l1be, l1m, l1v, dWf, dBf);
    init_zero<<<1, 256, 0, stream>>>(out, ctr);

    {
        const ushort* xbp = xb;
        const ushort* bf0x = wf + FR_L0X;
        const ushort* bf0h = wf + FR_L0H;
        const ushort* bf1x = wf + FR_L1X;
        const ushort* bf1h = wf + FR_L1H;
        void* args[] = { (void*)&xbp, (void*)&bf0x, (void*)&bf0h, (void*)&l0b,
                         (void*)&l0g, (void*)&l0be, (void*)&l0m, (void*)&l0v,
                         (void*)&bf1x, (void*)&bf1h, (void*)&l1b,
                         (void*)&z1, (void*)&h0s, (void*)&x1s, (void*)&h1s,
                         (void*)&ctr0, (void*)&ctr1, (void*)&ctr2 };
        hipLaunchCooperativeKernel((const void*)lstm_pipe, dim3(768), dim3(256),
                                   args, 0, stream);
    }

    pool_all<<<512, 256, 0, stream>>>(h1s, dWf, dBf, out);
}

// Round 14
// 360.935 us; speedup vs baseline: 4.4346x; 4.4346x over previous
//
#include <hip/hip_runtime.h>
#include <math.h>

typedef __attribute__((ext_vector_type(8))) short short8v;   // 8 bf16 = 4 VGPRs
typedef __attribute__((ext_vector_type(4))) float float4v;   // MFMA acc

constexpr int Bsz = 8, Tn = 16, CINc = 6, Fc = 64, NCc = 10;
constexpr int PIX = 8192;                 // 8*32*32 pixels per timestep
constexpr float BN_EPS = 1e-3f;

// weight-fragment region offsets (in ushort elements)
constexpr int FR_L0X = 0;                 // 2 chunks  (K=54 padded to 64)
constexpr int FR_L0H = 16384;             // 18 chunks (K=576)
constexpr int FR_L1X = 163840;            // 18 chunks
constexpr int FR_L1H = 311296;            // 18 chunks
constexpr int FR_TOTAL = 458752;

__device__ __forceinline__ ushort f2bf(float f) {
    union { float f; unsigned u; } v; v.f = f;
    unsigned r = v.u + 0x7FFFu + ((v.u >> 16) & 1u);   // RNE
    return (ushort)(r >> 16);
}
__device__ __forceinline__ float bf2f(ushort u) {
    union { unsigned u; float f; } v; v.u = ((unsigned)u) << 16; return v.f;
}
__device__ __forceinline__ float hsig(float x) {
    return fminf(fmaxf(0.2f * x + 0.5f, 0.0f), 1.0f);
}

#define GLDS(srcp, dstp) \
    __builtin_amdgcn_global_load_lds((const __attribute__((address_space(1))) void*)(srcp), \
                                     (__attribute__((address_space(3))) void*)(dstp), 16, 0, 0)

// ---------------- fused prep: x->bf16, weights->frags, init, dense-fold ----------------
__global__ __launch_bounds__(256) void prep_all(
    const float* __restrict__ in, ushort* __restrict__ xb,
    const float* __restrict__ W0x, const float* __restrict__ W0h,
    const float* __restrict__ W1x, const float* __restrict__ W1h,
    ushort* __restrict__ F,
    const float* __restrict__ dW, const float* __restrict__ dB,
    const float* __restrict__ g1, const float* __restrict__ be1,
    const float* __restrict__ mn1, const float* __restrict__ vr1,
    float* __restrict__ dWf, float* __restrict__ dBf,
    float* __restrict__ c0, float* __restrict__ c1,
    ushort* __restrict__ h00, ushort* __restrict__ h01,
    ushort* __restrict__ h10, ushort* __restrict__ h11,
    float* __restrict__ out)
{
    const int b = blockIdx.x, tid = threadIdx.x;
    __shared__ float sc[64], sh[64];

    if (b < 3072) {                       // prep_x
        int o = b * 256 + tid;
        if (o < Tn * PIX * CINc) {
            int t = o / (PIX * CINc);
            int rem = o - t * (PIX * CINc);
            int pix = rem / CINc, c = rem - pix * CINc;
            int bb = pix >> 10, p = pix & 1023;
            xb[o] = f2bf(in[((bb * Tn + t) * 1024 + p) * CINc + c]);
        }
    } else if (b < 4864) {                // prep_w
        int o = (b - 3072) * 256 + tid;
        if (o < FR_TOTAL) {
            const float* W; int K; int base;
            if (o < FR_L0H)      { W = W0x; K = 54;  base = FR_L0X; }
            else if (o < FR_L1X) { W = W0h; K = 576; base = FR_L0H; }
            else if (o < FR_L1H) { W = W1x; K = 576; base = FR_L1X; }
            else                 { W = W1h; K = 576; base = FR_L1H; }
            int r = o - base;
            int e = r & 7, lane = (r >> 3) & 63, j = (r >> 9) & 7, nh = (r >> 12) & 1, kc = r >> 13;
            int nt = ((j >> 1) << 2) + nh * 2 + (j & 1);
            int k = kc * 32 + ((lane >> 4) * 4) + (e & 3) + 16 * (e >> 2);
            int n = nt * 16 + (lane & 15);
            F[o] = (k < K) ? f2bf(W[k * 256 + n]) : (ushort)0;
        }
    } else if (b < 6912) {                // init states + out
        int i = (b - 4864) * 256 + tid;   // < 524288
        c0[i] = 0.f; c1[i] = 0.f;
        h00[i] = 0; h01[i] = 0; h10[i] = 0; h11[i] = 0;
        if (b == 4864 && tid < Bsz * NCc) out[tid] = 0.f;
    } else {                              // dense BN fold
        if (tid < 64) {
            float s = g1[tid] * rsqrtf(vr1[tid] + BN_EPS);
            sc[tid] = s; sh[tid] = be1[tid] - mn1[tid] * s;
        }
        __syncthreads();
        for (int i = tid; i < 640; i += 256) dWf[i] = sc[i / 10] * dW[i];
        if (tid < NCc) {
            float a = dB[tid];
            for (int f = 0; f < 64; ++f) a += sh[f] * dW[f * 10 + tid];
            dBf[tid] = a;
        }
    }
}

// ---------------- 3-stage wavefront step: 128-px tile x 64-zch quarter ----------------
// grp0 (blocks   0..255): layer-0 step t    (10 chunks: 1 x + 9 taps) -> h0, x1[t]
// grp1 (blocks 256..511): z1[t-1] = conv(x1[t-1],W1x)+b1 (9 taps) -> z1 frags (fp32)
// grp2 (blocks 512..767): layer-1 step t-2  (9 h-taps, acc init from z1) -> h1, h1s[t-2]
// Block: 128 pixels (4 rows x 32 cols) x gate-quarter nq (h-ch nq*16..+15 x 4 gates).
// Waves = 4 rows (wid = row); each wave 2 m-frags x 4 gate-frags = 8 acc frags.
// B per chunk = 8 KB (half of round-11's 16) -> L2 weight stream halved (77 MB/slot).
// A: 6x34x64ch halo in LDS once; one barrier per chunk (B glds dbuf drain only).
__global__ __launch_bounds__(256, 3) void step_tri(
    int t,
    const ushort* __restrict__ Xb,
    const ushort* __restrict__ Bf0X, const ushort* __restrict__ Bf0H,
    const float* __restrict__ b0,
    float* __restrict__ C0, const ushort* __restrict__ H0prev, ushort* __restrict__ H0cur,
    ushort* __restrict__ X1s,
    const float* __restrict__ g0, const float* __restrict__ be0,
    const float* __restrict__ mn0, const float* __restrict__ v0,
    const ushort* __restrict__ Bf1X, const ushort* __restrict__ Bf1H,
    const float* __restrict__ b1, float* __restrict__ Z1,
    float* __restrict__ C1, const ushort* __restrict__ H1prev, ushort* __restrict__ H1cur,
    ushort* __restrict__ H1s)
{
    const int grp = blockIdx.x >> 8;
    int s;
    if (grp == 0)      { s = t;     if (s >= Tn) return; }
    else if (grp == 1) { s = t - 1; if (s < 0 || s >= Tn) return; }
    else               { s = t - 2; if (s < 0) return; }

    __shared__ ushort Hh[204 * 68];       // 6x34 halo x 64ch (+4 pad): 27744 B
    __shared__ ushort Xh[204 * 8];        // grp0 x-halo: 3264 B
    __shared__ ushort Bs[2][4096];        // dbuf: 8 KB per chunk ([sub][gate][lane][e])

    const int tid = threadIdx.x;
    const int wid = tid >> 6, lane = tid & 63;   // wid = pixel row within tile
    const int bid = blockIdx.x & 255;
    const int bm = bid >> 2, nq = bid & 3;
    const int m0 = bm * 128;
    const int img = m0 >> 10;
    const int py0 = (m0 & 1023) >> 5;     // first of 4 rows

    const ushort* __restrict__ Xt   = Xb + s * PIX * CINc;
    const ushort* __restrict__ X1t  = X1s + (size_t)s * (PIX * Fc);
    float* __restrict__ Zp = Z1 + (((size_t)s * 64 + bm) * 4 + nq) * 8192;
    const int TOT = (grp == 0) ? 10 : 9;
    const ushort* __restrict__ Psrc = (grp == 0) ? H0prev : (grp == 1 ? X1t : H1prev);

    const int jsel = nq & 1, nhq = nq >> 1;

    auto bblock = [&](int q, int sub) -> const ushort* {
        if (grp == 0) {
            if (q == 0) return Bf0X + ((sub * 2 + nhq) << 12);
            int tp = q - 1;
            return Bf0H + ((4 * tp + 2 * sub + nhq) << 12);
        } else if (grp == 1) {
            return Bf1X + ((4 * q + 2 * sub + nhq) << 12);
        }
        return Bf1H + ((4 * q + 2 * sub + nhq) << 12);
    };
    // wave wid stages gate-frag g=wid for both K-sub-chunks (2 GLDS/thread/chunk)
    auto stageB = [&](int q, int buf) {
        const int j = (wid << 1) + jsel;
#pragma unroll
        for (int sub = 0; sub < 2; ++sub) {
            const ushort* src = bblock(q, sub) + (j << 9) + (lane << 3);
            GLDS(src, &Bs[buf][(sub << 11) + (wid << 9)]);
        }
    };

    // ---- prologue: B(0) first (latency hidden under halo gather), then halos ----
    stageB(0, 0);
#pragma unroll
    for (int u = 0; u < 7; ++u) {         // 64-ch halo: 204 slots x 8 x 16B
        int idx = tid + u * 256;
        if (idx < 1632) {
            int slot = idx >> 3, part = idx & 7;
            int yy = slot / 34, xx = slot - yy * 34;
            int gy = py0 - 1 + yy, gx = xx - 1;
            uint4 v = make_uint4(0u, 0u, 0u, 0u);
            if ((unsigned)gy < 32u && (unsigned)gx < 32u)
                v = *(const uint4*)(Psrc + (((img << 10) + gy * 32 + gx) << 6) + part * 8);
            ushort* d = &Hh[slot * 68 + part * 8];
            *(uint2*)(d)     = make_uint2(v.x, v.y);
            *(uint2*)(d + 4) = make_uint2(v.z, v.w);
        }
    }
    if (grp == 0) {                       // x-halo: 204 slots x 6 ch
#pragma unroll
        for (int u = 0; u < 5; ++u) {
            int idx = tid + u * 256;
            if (idx < 1224) {
                int slot = idx / 6, c = idx - slot * 6;
                int yy = slot / 34, xx = slot - yy * 34;
                int gy = py0 - 1 + yy, gx = xx - 1;
                ushort v = 0;
                if ((unsigned)gy < 32u && (unsigned)gx < 32u)
                    v = Xt[((img << 10) + gy * 32 + gx) * 6 + c];
                Xh[slot * 8 + c] = v;
            }
        }
    }

    // acc: 8 frags = gate g (0..3) x m-frag mf (0..1), index a = g*2 + mf
    const int ch = (nq << 4) + (lane & 15);       // h-channel 0..63
    float4v acc[8];
    if (grp == 2) {
#pragma unroll
        for (int a = 0; a < 8; ++a)
            acc[a] = *(const float4v*)(Zp + (((wid * 8 + a) * 64 + lane) << 2));
    } else {
        const float* __restrict__ bias = (grp == 0) ? b0 : b1;
#pragma unroll
        for (int g = 0; g < 4; ++g) {
            const float bb = bias[(g << 6) + ch];
#pragma unroll
            for (int r = 0; r < 4; ++r) { acc[g * 2 + 0][r] = bb; acc[g * 2 + 1][r] = bb; }
        }
    }

    const int x0 = lane & 15, x1 = x0 + 16;       // cols of the two m-frags (row = wid)
    const int coff = (lane >> 4) << 2;            // c base (ushorts)

    auto xfrag = [&](int x, int half) -> short8v {
        union { ushort e[8]; short8v v; } r;
#pragma unroll
        for (int e = 0; e < 8; ++e) {
            int kg = half * 32 + coff + (e & 3) + 16 * (e >> 2);
            ushort val = 0;
            if (kg < 54) {
                int tap = kg / 6, c = kg - tap * 6;
                int dy = tap / 3 - 1, dxx = tap % 3 - 1;
                val = Xh[((wid + dy + 1) * 34 + (x + dxx + 1)) * 8 + c];
            }
            r.e[e] = val;
        }
        return r.v;
    };

    __syncthreads();    // publish halos; drains B(0) glds

    for (int q = 0; q < TOT; ++q) {
        if (q + 1 < TOT) stageB(q + 1, (q + 1) & 1);   // full chunk body in flight

        union { struct { uint2 lo, hi; } u; short8v s; } a00, a10, a01, a11;
        if (grp == 0 && q == 0) {
            a00.s = xfrag(x0, 0); a01.s = xfrag(x0, 1);
            a10.s = xfrag(x1, 0); a11.s = xfrag(x1, 1);
        } else {
            const int tap = (grp == 0) ? q - 1 : q;
            const int dy = tap / 3 - 1, dxx = tap % 3 - 1;
            const ushort* h0r = &Hh[((wid + dy + 1) * 34 + (x0 + dxx + 1)) * 68 + coff];
            const ushort* h1r = &Hh[((wid + dy + 1) * 34 + (x1 + dxx + 1)) * 68 + coff];
            a00.u.lo = *(const uint2*)(h0r);      a00.u.hi = *(const uint2*)(h0r + 16);
            a01.u.lo = *(const uint2*)(h0r + 32); a01.u.hi = *(const uint2*)(h0r + 48);
            a10.u.lo = *(const uint2*)(h1r);      a10.u.hi = *(const uint2*)(h1r + 16);
            a11.u.lo = *(const uint2*)(h1r + 32); a11.u.hi = *(const uint2*)(h1r + 48);
        }

        const ushort* bs = &Bs[q & 1][0];
        union { uint4 u; short8v s; } b0r[4], b1r[4];
#pragma unroll
        for (int g = 0; g < 4; ++g) {
            b0r[g].u = *(const uint4*)(bs + (g << 9) + (lane << 3));
            b1r[g].u = *(const uint4*)(bs + 2048 + (g << 9) + (lane << 3));
        }

#pragma unroll
        for (int g = 0; g < 4; ++g) {
            acc[g * 2 + 0] = __builtin_amdgcn_mfma_f32_16x16x32_bf16(a00.s, b0r[g].s, acc[g * 2 + 0], 0, 0, 0);
            acc[g * 2 + 1] = __builtin_amdgcn_mfma_f32_16x16x32_bf16(a10.s, b0r[g].s, acc[g * 2 + 1], 0, 0, 0);
        }
#pragma unroll
        for (int g = 0; g < 4; ++g) {
            acc[g * 2 + 0] = __builtin_amdgcn_mfma_f32_16x16x32_bf16(a01.s, b1r[g].s, acc[g * 2 + 0], 0, 0, 0);
            acc[g * 2 + 1] = __builtin_amdgcn_mfma_f32_16x16x32_bf16(a11.s, b1r[g].s, acc[g * 2 + 1], 0, 0, 0);
        }

        __syncthreads();   // drains glds of B(q+1); ends reads of Bs[q&1]
    }

    // ---------------- epilogues ----------------
    if (grp == 1) {                             // store z1 fragments (fp32, coalesced)
#pragma unroll
        for (int a = 0; a < 8; ++a) {
            float4 o;
            o.x = acc[a][0]; o.y = acc[a][1]; o.z = acc[a][2]; o.w = acc[a][3];
            *(float4*)(Zp + (((wid * 8 + a) * 64 + lane) << 2)) = o;
        }
        return;
    }

    // LSTM gate epilogue: g=0 -> i, 1 -> f, 2 -> g, 3 -> o
    float* __restrict__ C  = (grp == 0) ? C0 : C1;
    ushort* __restrict__ Hc = (grp == 0) ? H0cur : H1cur;
    ushort* __restrict__ Seq = (grp == 0) ? (X1s + (size_t)s * (PIX * Fc))
                                          : (H1s + (size_t)s * (PIX * Fc));
    float inv = 0.f, mu = 0.f, bet = 0.f;
    if (grp == 0) {
        inv = g0[ch] * rsqrtf(v0[ch] + BN_EPS);
        mu = mn0[ch]; bet = be0[ch];
    }
#pragma unroll
    for (int mf = 0; mf < 2; ++mf) {
#pragma unroll
        for (int r = 0; r < 4; ++r) {
            const int p = m0 + wid * 32 + mf * 16 + (lane >> 4) * 4 + r;
            const int o = p * 64 + ch;
            float zi = acc[0 + mf][r];
            float zf = acc[2 + mf][r];
            float zg = acc[4 + mf][r];
            float zo = acc[6 + mf][r];
            float cv = hsig(zf) * C[o] + hsig(zi) * tanhf(zg);
            C[o] = cv;
            float h = hsig(zo) * tanhf(cv);
            Hc[o] = f2bf(h);
            Seq[o] = (grp == 0) ? f2bf((h - mu) * inv + bet) : f2bf(h);
        }
    }
}

// ---------------- pool over all t: h1 @ dWf (BN folded) -> softmax -> mean ----------------
__global__ __launch_bounds__(256) void pool_all(
    const ushort* __restrict__ H1seq, const float* __restrict__ dWf,
    const float* __restrict__ dBf, float* __restrict__ out)
{
    __shared__ float wlds[640];
    __shared__ float accs[NCc];
    const int tid = threadIdx.x;
    for (int i = tid; i < 640; i += 256) wlds[i] = dWf[i];
    if (tid < NCc) accs[tid] = 0.f;
    __syncthreads();

    const int gid = blockIdx.x * 256 + tid;   // 512 blocks x 256 = 131072
    const int b = (gid & 8191) >> 10;

    float logit[NCc];
#pragma unroll
    for (int c = 0; c < NCc; ++c) logit[c] = dBf[c];
    const ushort* hp = H1seq + (size_t)gid * Fc;
#pragma unroll
    for (int f0 = 0; f0 < 8; ++f0) {
        union { uint4 u; ushort s[8]; } hu;
        hu.u = *(const uint4*)(hp + f0 * 8);
#pragma unroll
        for (int j = 0; j < 8; ++j) {
            float v = bf2f(hu.s[j]);
            const float* w = &wlds[(f0 * 8 + j) * 10];
#pragma unroll
            for (int c = 0; c < NCc; ++c) logit[c] += v * w[c];
        }
    }
    float mx = logit[0];
#pragma unroll
    for (int c = 1; c < NCc; ++c) mx = fmaxf(mx, logit[c]);
    float p[NCc]; float ssum = 0.f;
#pragma unroll
    for (int c = 0; c < NCc; ++c) { p[c] = expf(logit[c] - mx); ssum += p[c]; }
    float invs = 1.f / ssum;

#pragma unroll
    for (int c = 0; c < NCc; ++c) {
        float v = p[c] * invs;
        v += __shfl_xor(v, 1);
        v += __shfl_xor(v, 2);
        v += __shfl_xor(v, 4);
        v += __shfl_xor(v, 8);
        v += __shfl_xor(v, 16);
        v += __shfl_xor(v, 32);
        if ((tid & 63) == 0) atomicAdd(&accs[c], v);
    }
    __syncthreads();
    if (tid < NCc)
        atomicAdd(&out[b * NCc + tid], accs[tid] * (1.0f / 16384.0f));
}

extern "C" void kernel_launch(void* const* d_in, const int* in_sizes, int n_in,
                              void* d_out, int out_size, void* d_ws, size_t ws_size,
                              hipStream_t stream) {
    const float* in    = (const float*)d_in[0];
    const float* l0Wx  = (const float*)d_in[1];
    const float* l0Wh  = (const float*)d_in[2];
    const float* l0b   = (const float*)d_in[3];
    const float* l0g   = (const float*)d_in[4];
    const float* l0be  = (const float*)d_in[5];
    const float* l0m   = (const float*)d_in[6];
    const float* l0v   = (const float*)d_in[7];
    const float* l1Wx  = (const float*)d_in[8];
    const float* l1Wh  = (const float*)d_in[9];
    const float* l1b   = (const float*)d_in[10];
    const float* l1g   = (const float*)d_in[11];
    const float* l1be  = (const float*)d_in[12];
    const float* l1m   = (const float*)d_in[13];
    const float* l1v   = (const float*)d_in[14];
    const float* dW    = (const float*)d_in[15];
    const float* dB    = (const float*)d_in[16];
    float* out = (float*)d_out;

    float* ws   = (float*)d_ws;
    float* c0   = ws;                        // 524,288 f
    float* c1   = c0 + 524288;
    float* z1   = c1 + 524288;               // 33,554,432 f (134 MB) z1 fragments
    ushort* us  = (ushort*)(z1 + 33554432);
    ushort* h0p0 = us;                       // h ping-pong buffers (bf16)
    ushort* h0p1 = h0p0 + 524288;
    ushort* h1p0 = h0p1 + 524288;
    ushort* h1p1 = h1p0 + 524288;
    ushort* xb  = h1p1 + 524288;             // 786,432 us
    ushort* x1  = xb + 786432;               // 16*524,288 us (BN'd layer-0 output)
    ushort* h1s = x1 + 8388608;              // 16*524,288 us (layer-1 h sequence)
    ushort* wf  = h1s + 8388608;             // 458,752 us
    float* dWf  = (float*)(wf + 458752);     // 640 f (BN-folded dense W)
    float* dBf  = dWf + 640;                 // 10 f

    ushort* h0p[2] = { h0p0, h0p1 };
    ushort* h1p[2] = { h1p0, h1p1 };

    prep_all<<<6913, 256, 0, stream>>>(in, xb, l0Wx, l0Wh, l1Wx, l1Wh, wf,
                                       dW, dB, l1g, l1be, l1m, l1v, dWf, dBf,
                                       c0, c1, h0p0, h0p1, h1p0, h1p1, out);

    // 3-stage wavefront: slot t = { L0 step t, z1[t-1], L1 step t-2 }
    for (int t = 0; t < Tn + 2; ++t) {
        step_tri<<<768, 256, 0, stream>>>(
            t, xb,
            wf + FR_L0X, wf + FR_L0H, l0b,
            c0, h0p[t & 1], h0p[(t + 1) & 1], x1,
            l0g, l0be, l0m, l0v,
            wf + FR_L1X, wf + FR_L1H, l1b, z1,
            c1, h1p[t & 1], h1p[(t + 1) & 1], h1s);
    }
    pool_all<<<512, 256, 0, stream>>>(h1s, dWf, dBf, out);
}

// Round 15
// 327.927 us; speedup vs baseline: 4.8810x; 1.1007x over previous
//
#include <hip/hip_runtime.h>
#include <math.h>

typedef __attribute__((ext_vector_type(8))) short short8v;   // 8 bf16 = 4 VGPRs
typedef __attribute__((ext_vector_type(4))) float float4v;   // MFMA acc

constexpr int Bsz = 8, Tn = 16, CINc = 6, Fc = 64, NCc = 10;
constexpr int PIX = 8192;                 // 8*32*32 pixels per timestep
constexpr float BN_EPS = 1e-3f;

// weight-fragment region offsets (in ushort elements)
constexpr int FR_L0X = 0;                 // 2 chunks  (K=54 padded to 64)
constexpr int FR_L0H = 16384;             // 18 chunks (K=576)
constexpr int FR_L1X = 163840;            // 18 chunks
constexpr int FR_L1H = 311296;            // 18 chunks
constexpr int FR_TOTAL = 458752;

__device__ __forceinline__ ushort f2bf(float f) {
    union { float f; unsigned u; } v; v.f = f;
    unsigned r = v.u + 0x7FFFu + ((v.u >> 16) & 1u);   // RNE
    return (ushort)(r >> 16);
}
__device__ __forceinline__ float bf2f(ushort u) {
    union { unsigned u; float f; } v; v.u = ((unsigned)u) << 16; return v.f;
}
__device__ __forceinline__ float hsig(float x) {
    return fminf(fmaxf(0.2f * x + 0.5f, 0.0f), 1.0f);
}

#define GLDS(srcp, dstp) \
    __builtin_amdgcn_global_load_lds((const __attribute__((address_space(1))) void*)(srcp), \
                                     (__attribute__((address_space(3))) void*)(dstp), 16, 0, 0)

// ---------------- fused prep: x->bf16, weights->frags, init, dense-fold ----------------
__global__ __launch_bounds__(256) void prep_all(
    const float* __restrict__ in, ushort* __restrict__ xb,
    const float* __restrict__ W0x, const float* __restrict__ W0h,
    const float* __restrict__ W1x, const float* __restrict__ W1h,
    ushort* __restrict__ F,
    const float* __restrict__ dW, const float* __restrict__ dB,
    const float* __restrict__ g1, const float* __restrict__ be1,
    const float* __restrict__ mn1, const float* __restrict__ vr1,
    float* __restrict__ dWf, float* __restrict__ dBf,
    float* __restrict__ c0, float* __restrict__ c1,
    ushort* __restrict__ h00, ushort* __restrict__ h01,
    ushort* __restrict__ h10, ushort* __restrict__ h11,
    float* __restrict__ out)
{
    const int b = blockIdx.x, tid = threadIdx.x;
    __shared__ float sc[64], sh[64];

    if (b < 3072) {                       // prep_x
        int o = b * 256 + tid;
        if (o < Tn * PIX * CINc) {
            int t = o / (PIX * CINc);
            int rem = o - t * (PIX * CINc);
            int pix = rem / CINc, c = rem - pix * CINc;
            int bb = pix >> 10, p = pix & 1023;
            xb[o] = f2bf(in[((bb * Tn + t) * 1024 + p) * CINc + c]);
        }
    } else if (b < 4864) {                // prep_w
        int o = (b - 3072) * 256 + tid;
        if (o < FR_TOTAL) {
            const float* W; int K; int base;
            if (o < FR_L0H)      { W = W0x; K = 54;  base = FR_L0X; }
            else if (o < FR_L1X) { W = W0h; K = 576; base = FR_L0H; }
            else if (o < FR_L1H) { W = W1x; K = 576; base = FR_L1X; }
            else                 { W = W1h; K = 576; base = FR_L1H; }
            int r = o - base;
            int e = r & 7, lane = (r >> 3) & 63, j = (r >> 9) & 7, nh = (r >> 12) & 1, kc = r >> 13;
            int nt = ((j >> 1) << 2) + nh * 2 + (j & 1);
            int k = kc * 32 + ((lane >> 4) * 4) + (e & 3) + 16 * (e >> 2);
            int n = nt * 16 + (lane & 15);
            F[o] = (k < K) ? f2bf(W[k * 256 + n]) : (ushort)0;
        }
    } else if (b < 6912) {                // init states + out
        int i = (b - 4864) * 256 + tid;   // < 524288
        c0[i] = 0.f; c1[i] = 0.f;
        h00[i] = 0; h01[i] = 0; h10[i] = 0; h11[i] = 0;
        if (b == 4864 && tid < Bsz * NCc) out[tid] = 0.f;
    } else {                              // dense BN fold
        if (tid < 64) {
            float s = g1[tid] * rsqrtf(vr1[tid] + BN_EPS);
            sc[tid] = s; sh[tid] = be1[tid] - mn1[tid] * s;
        }
        __syncthreads();
        for (int i = tid; i < 640; i += 256) dWf[i] = sc[i / 10] * dW[i];
        if (tid < NCc) {
            float a = dB[tid];
            for (int f = 0; f < 64; ++f) a += sh[f] * dW[f * 10 + tid];
            dBf[tid] = a;
        }
    }
}

// ---------------- 3-stage wavefront step: halo-LDS A, GLDS-staged B, 1 barrier/chunk ----
// (round-11 measured-best structure, restored verbatim)
// grp0 (blocks   0..255): layer-0 step t    (10 chunks: 1 x + 9 taps) -> h0, x1[t]
// grp1 (blocks 256..511): z1[t-1] = conv(x1[t-1],W1x)+b1 (9 taps) -> z1 frags (fp32)
// grp2 (blocks 512..767): layer-1 step t-2  (9 h-taps, acc init from z1) -> h1, h1s[t-2]
// Block tile: 64 pixels (2 rows x 32 cols) x 128 gate-paired ch (nh half).
// A input staged ONCE as a 4x34x64ch halo in LDS; per-tap A frags are direct b64 LDS
// reads at shifted offsets. One barrier per chunk (B glds dbuf drain only).
__global__ __launch_bounds__(256, 3) void step_tri(
    int t,
    const ushort* __restrict__ Xb,
    const ushort* __restrict__ Bf0X, const ushort* __restrict__ Bf0H,
    const float* __restrict__ b0,
    float* __restrict__ C0, const ushort* __restrict__ H0prev, ushort* __restrict__ H0cur,
    ushort* __restrict__ X1s,
    const float* __restrict__ g0, const float* __restrict__ be0,
    const float* __restrict__ mn0, const float* __restrict__ v0,
    const ushort* __restrict__ Bf1X, const ushort* __restrict__ Bf1H,
    const float* __restrict__ b1, float* __restrict__ Z1,
    float* __restrict__ C1, const ushort* __restrict__ H1prev, ushort* __restrict__ H1cur,
    ushort* __restrict__ H1s)
{
    const int grp = blockIdx.x >> 8;
    int s;
    if (grp == 0)      { s = t;     if (s >= Tn) return; }
    else if (grp == 1) { s = t - 1; if (s < 0 || s >= Tn) return; }
    else               { s = t - 2; if (s < 0) return; }

    __shared__ ushort Hh[136 * 68];       // 64-ch halo: [yy*34+xx][68] (64 used, 68 = bank spread)
    __shared__ ushort Xh[136 * 8];        // grp0 x-halo: [yy*34+xx][8] (6 used)
    __shared__ ushort Bs[2][8192];        // dbuf: 16KB B pair

    const int tid = threadIdx.x;
    const int wid = tid >> 6, lane = tid & 63;
    const int wm = wid >> 1, wn = wid & 1;
    const int bid = blockIdx.x & 255;
    const int bm = bid >> 1, nh = bid & 1;
    const int m0 = bm * 64;
    const int img = m0 >> 10;
    const int py0 = (m0 & 1023) >> 5;     // first of the 2 pixel rows

    // per-group bindings
    const ushort* __restrict__ Xt   = Xb + s * PIX * CINc;               // grp0 x-path
    const ushort* __restrict__ X1t  = X1s + (size_t)s * (PIX * Fc);      // grp1 input
    float* __restrict__ Zp = Z1 + (((size_t)s * 128 + bm) * 2 + nh) * 8192;  // grp1 out / grp2 in
    const int TOT = (grp == 0) ? 10 : 9;
    const ushort* __restrict__ Psrc = (grp == 0) ? H0prev : (grp == 1 ? X1t : H1prev);

    auto stageB = [&](int q, int buf) {
        const ushort *g0p, *g1p;
        if (grp == 0) {
            if (q == 0) { g0p = Bf0X + (nh << 12); g1p = Bf0X + ((2 + nh) << 12); }
            else { int tp = q - 1;
                   g0p = Bf0H + ((4 * tp + nh) << 12);
                   g1p = Bf0H + ((4 * tp + 2 + nh) << 12); }
        } else if (grp == 1) {
            g0p = Bf1X + ((4 * q + nh) << 12);
            g1p = Bf1X + ((4 * q + 2 + nh) << 12);
        } else {
            g0p = Bf1H + ((4 * q + nh) << 12);
            g1p = Bf1H + ((4 * q + 2 + nh) << 12);
        }
        ushort* d = &Bs[buf][0];
        GLDS(g0p + (tid << 3),         d + wid * 512);
        GLDS(g0p + ((256 + tid) << 3), d + 2048 + wid * 512);
        GLDS(g1p + (tid << 3),         d + 4096 + wid * 512);
        GLDS(g1p + ((256 + tid) << 3), d + 4096 + 2048 + wid * 512);
    };

    // ---- prologue: stage B(0) + halo(s) ----
    stageB(0, 0);
    // 64-ch halo: 136 slots x 8 parts of 16B = 1088 units
#pragma unroll
    for (int u = 0; u < 5; ++u) {
        int idx = tid + u * 256;
        if (idx < 1088) {
            int slot = idx >> 3, part = idx & 7;
            int yy = slot / 34, xx = slot - yy * 34;
            int gy = py0 - 1 + yy, gx = xx - 1;
            uint4 v = make_uint4(0u, 0u, 0u, 0u);
            if ((unsigned)gy < 32u && (unsigned)gx < 32u)
                v = *(const uint4*)(Psrc + (((img << 10) + gy * 32 + gx) << 6) + part * 8);
            ushort* d = &Hh[slot * 68 + part * 8];
            *(uint2*)(d)     = make_uint2(v.x, v.y);   // 8B-aligned (row stride 136B)
            *(uint2*)(d + 4) = make_uint2(v.z, v.w);
        }
    }
    if (grp == 0) {                       // x-halo: 136 slots x 6 ch
#pragma unroll
        for (int u = 0; u < 4; ++u) {
            int idx = tid + u * 256;
            if (idx < 816) {
                int slot = idx / 6, c = idx - slot * 6;
                int yy = slot / 34, xx = slot - yy * 34;
                int gy = py0 - 1 + yy, gx = xx - 1;
                ushort v = 0;
                if ((unsigned)gy < 32u && (unsigned)gx < 32u)
                    v = Xt[((img << 10) + gy * 32 + gx) * 6 + c];
                Xh[slot * 8 + c] = v;
            }
        }
    }

    // acc: 8 frags = gate g (0..3) x m-frag mf (0..1), index a = g*2 + mf
    float4v acc[8];
    if (grp == 2) {
#pragma unroll
        for (int a = 0; a < 8; ++a)
            acc[a] = *(const float4v*)(Zp + (((wid * 8 + a) * 64 + lane) << 2));
    } else {
        const float* __restrict__ bias = (grp == 0) ? b0 : b1;
        const int hch = (nh * 2 + wn) * 16 + (lane & 15);
#pragma unroll
        for (int g = 0; g < 4; ++g) {
            const float bb = bias[g * 64 + hch];
#pragma unroll
            for (int r = 0; r < 4; ++r) { acc[g * 2 + 0][r] = bb; acc[g * 2 + 1][r] = bb; }
        }
    }

    // lane pixel coords for the two m-frags
    const int p0x = wm * 32 + (lane & 15);        // mf=0
    const int p1x = p0x + 16;                     // mf=1
    const int y0r = p0x >> 5, x0c = p0x & 31;
    const int y1r = p1x >> 5, x1c = p1x & 31;
    const int coff = (lane >> 4) << 2;            // c base (ushorts)

    // x-path frag builder (grp0 chunk 0): per-element gather from Xh
    auto xfrag = [&](int lry, int lcx, int half) -> short8v {
        union { ushort e[8]; short8v v; } r;
#pragma unroll
        for (int e = 0; e < 8; ++e) {
            int kg = half * 32 + coff + (e & 3) + 16 * (e >> 2);
            ushort val = 0;
            if (kg < 54) {
                int tap = kg / 6, c = kg - tap * 6;
                int dy = tap / 3 - 1, dxx = tap % 3 - 1;
                val = Xh[((lry + dy + 1) * 34 + (lcx + dxx + 1)) * 8 + c];
            }
            r.e[e] = val;
        }
        return r.v;
    };

    __syncthreads();    // publish halos; drains B(0) glds

    for (int q = 0; q < TOT; ++q) {
        if (q + 1 < TOT) stageB(q + 1, (q + 1) & 1);   // full chunk body in flight

        union { struct { uint2 lo, hi; } u; short8v s; } a00, a10, a01, a11;
        if (grp == 0 && q == 0) {
            a00.s = xfrag(y0r, x0c, 0); a01.s = xfrag(y0r, x0c, 1);
            a10.s = xfrag(y1r, x1c, 0); a11.s = xfrag(y1r, x1c, 1);
        } else {
            const int tap = (grp == 0) ? q - 1 : q;
            const int dy = tap / 3 - 1, dxx = tap % 3 - 1;
            const ushort* h0r = &Hh[((y0r + dy + 1) * 34 + (x0c + dxx + 1)) * 68 + coff];
            const ushort* h1r = &Hh[((y1r + dy + 1) * 34 + (x1c + dxx + 1)) * 68 + coff];
            a00.u.lo = *(const uint2*)(h0r);      a00.u.hi = *(const uint2*)(h0r + 16);
            a01.u.lo = *(const uint2*)(h0r + 32); a01.u.hi = *(const uint2*)(h0r + 48);
            a10.u.lo = *(const uint2*)(h1r);      a10.u.hi = *(const uint2*)(h1r + 16);
            a11.u.lo = *(const uint2*)(h1r + 32); a11.u.hi = *(const uint2*)(h1r + 48);
        }

        const ushort* bs = &Bs[q & 1][0];
        union { uint4 u; short8v s; } b0r[4], b1r[4];
#pragma unroll
        for (int g = 0; g < 4; ++g) {
            const int j = g * 2 + wn;
            b0r[g].u = *(const uint4*)(bs + ((j * 64 + lane) << 3));
            b1r[g].u = *(const uint4*)(bs + 4096 + ((j * 64 + lane) << 3));
        }

#pragma unroll
        for (int g = 0; g < 4; ++g) {
            acc[g * 2 + 0] = __builtin_amdgcn_mfma_f32_16x16x32_bf16(a00.s, b0r[g].s, acc[g * 2 + 0], 0, 0, 0);
            acc[g * 2 + 1] = __builtin_amdgcn_mfma_f32_16x16x32_bf16(a10.s, b0r[g].s, acc[g * 2 + 1], 0, 0, 0);
        }
#pragma unroll
        for (int g = 0; g < 4; ++g) {
            acc[g * 2 + 0] = __builtin_amdgcn_mfma_f32_16x16x32_bf16(a01.s, b1r[g].s, acc[g * 2 + 0], 0, 0, 0);
            acc[g * 2 + 1] = __builtin_amdgcn_mfma_f32_16x16x32_bf16(a11.s, b1r[g].s, acc[g * 2 + 1], 0, 0, 0);
        }

        __syncthreads();   // drains glds of B(q+1); ends reads of Bs[q&1]
    }

    // ---------------- epilogues ----------------
    if (grp == 1) {                             // store z1 fragments (fp32, coalesced)
#pragma unroll
        for (int a = 0; a < 8; ++a) {
            float4 o;
            o.x = acc[a][0]; o.y = acc[a][1]; o.z = acc[a][2]; o.w = acc[a][3];
            *(float4*)(Zp + (((wid * 8 + a) * 64 + lane) << 2)) = o;
        }
        return;
    }

    // LSTM gate epilogue: g=0 -> i, 1 -> f, 2 -> g, 3 -> o
    float* __restrict__ C  = (grp == 0) ? C0 : C1;
    ushort* __restrict__ Hc = (grp == 0) ? H0cur : H1cur;
    ushort* __restrict__ Seq = (grp == 0) ? (X1s + (size_t)s * (PIX * Fc))
                                          : (H1s + (size_t)s * (PIX * Fc));
    const int ch = (nh * 2 + wn) * 16 + (lane & 15);   // h-channel 0..63
    float inv = 0.f, mu = 0.f, bet = 0.f;
    if (grp == 0) {
        inv = g0[ch] * rsqrtf(v0[ch] + BN_EPS);
        mu = mn0[ch]; bet = be0[ch];
    }
#pragma unroll
    for (int mf = 0; mf < 2; ++mf) {
#pragma unroll
        for (int r = 0; r < 4; ++r) {
            const int p = m0 + wm * 32 + mf * 16 + (lane >> 4) * 4 + r;
            const int o = p * 64 + ch;
            float zi = acc[0 + mf][r];
            float zf = acc[2 + mf][r];
            float zg = acc[4 + mf][r];
            float zo = acc[6 + mf][r];
            float cv = hsig(zf) * C[o] + hsig(zi) * tanhf(zg);
            C[o] = cv;
            float h = hsig(zo) * tanhf(cv);
            Hc[o] = f2bf(h);
            Seq[o] = (grp == 0) ? f2bf((h - mu) * inv + bet) : f2bf(h);
        }
    }
}

// ---------------- pool over all t: h1 @ dWf (BN folded) -> softmax -> mean ----------------
__global__ __launch_bounds__(256) void pool_all(
    const ushort* __restrict__ H1seq, const float* __restrict__ dWf,
    const float* __restrict__ dBf, float* __restrict__ out)
{
    __shared__ float wlds[640];
    __shared__ float accs[NCc];
    const int tid = threadIdx.x;
    for (int i = tid; i < 640; i += 256) wlds[i] = dWf[i];
    if (tid < NCc) accs[tid] = 0.f;
    __syncthreads();

    const int gid = blockIdx.x * 256 + tid;   // 512 blocks x 256 = 131072
    const int b = (gid & 8191) >> 10;          // uniform per block

    float logit[NCc];
#pragma unroll
    for (int c = 0; c < NCc; ++c) logit[c] = dBf[c];
    const ushort* hp = H1seq + (size_t)gid * Fc;
#pragma unroll
    for (int f0 = 0; f0 < 8; ++f0) {
        union { uint4 u; ushort s[8]; } hu;
        hu.u = *(const uint4*)(hp + f0 * 8);
#pragma unroll
        for (int j = 0; j < 8; ++j) {
            float v = bf2f(hu.s[j]);
            const float* w = &wlds[(f0 * 8 + j) * 10];
#pragma unroll
            for (int c = 0; c < NCc; ++c) logit[c] += v * w[c];
        }
    }
    float mx = logit[0];
#pragma unroll
    for (int c = 1; c < NCc; ++c) mx = fmaxf(mx, logit[c]);
    float p[NCc]; float ssum = 0.f;
#pragma unroll
    for (int c = 0; c < NCc; ++c) { p[c] = expf(logit[c] - mx); ssum += p[c]; }
    float invs = 1.f / ssum;

    // wave butterfly reduction per class, then one LDS atomic per wave
#pragma unroll
    for (int c = 0; c < NCc; ++c) {
        float v = p[c] * invs;
        v += __shfl_xor(v, 1);
        v += __shfl_xor(v, 2);
        v += __shfl_xor(v, 4);
        v += __shfl_xor(v, 8);
        v += __shfl_xor(v, 16);
        v += __shfl_xor(v, 32);
        if ((tid & 63) == 0) atomicAdd(&accs[c], v);
    }
    __syncthreads();
    if (tid < NCc)
        atomicAdd(&out[b * NCc + tid], accs[tid] * (1.0f / 16384.0f));
}

extern "C" void kernel_launch(void* const* d_in, const int* in_sizes, int n_in,
                              void* d_out, int out_size, void* d_ws, size_t ws_size,
                              hipStream_t stream) {
    const float* in    = (const float*)d_in[0];
    const float* l0Wx  = (const float*)d_in[1];
    const float* l0Wh  = (const float*)d_in[2];
    const float* l0b   = (const float*)d_in[3];
    const float* l0g   = (const float*)d_in[4];
    const float* l0be  = (const float*)d_in[5];
    const float* l0m   = (const float*)d_in[6];
    const float* l0v   = (const float*)d_in[7];
    const float* l1Wx  = (const float*)d_in[8];
    const float* l1Wh  = (const float*)d_in[9];
    const float* l1b   = (const float*)d_in[10];
    const float* l1g   = (const float*)d_in[11];
    const float* l1be  = (const float*)d_in[12];
    const float* l1m   = (const float*)d_in[13];
    const float* l1v   = (const float*)d_in[14];
    const float* dW    = (const float*)d_in[15];
    const float* dB    = (const float*)d_in[16];
    float* out = (float*)d_out;

    float* ws   = (float*)d_ws;
    float* c0   = ws;                        // 524,288 f
    float* c1   = c0 + 524288;
    float* z1   = c1 + 524288;               // 33,554,432 f (134 MB) z1 fragments
    ushort* us  = (ushort*)(z1 + 33554432);
    ushort* h0p0 = us;                       // h ping-pong buffers (bf16)
    ushort* h0p1 = h0p0 + 524288;
    ushort* h1p0 = h0p1 + 524288;
    ushort* h1p1 = h1p0 + 524288;
    ushort* xb  = h1p1 + 524288;             // 786,432 us
    ushort* x1  = xb + 786432;               // 16*524,288 us (BN'd layer-0 output)
    ushort* h1s = x1 + 8388608;              // 16*524,288 us (layer-1 h sequence)
    ushort* wf  = h1s + 8388608;             // 458,752 us
    float* dWf  = (float*)(wf + 458752);     // 640 f (BN-folded dense W)
    float* dBf  = dWf + 640;                 // 10 f

    ushort* h0p[2] = { h0p0, h0p1 };
    ushort* h1p[2] = { h1p0, h1p1 };

    prep_all<<<6913, 256, 0, stream>>>(in, xb, l0Wx, l0Wh, l1Wx, l1Wh, wf,
                                       dW, dB, l1g, l1be, l1m, l1v, dWf, dBf,
                                       c0, c1, h0p0, h0p1, h1p0, h1p1, out);

    // 3-stage wavefront: slot t = { L0 step t, z1[t-1], L1 step t-2 }
    for (int t = 0; t < Tn + 2; ++t) {
        step_tri<<<768, 256, 0, stream>>>(
            t, xb,
            wf + FR_L0X, wf + FR_L0H, l0b,
            c0, h0p[t & 1], h0p[(t + 1) & 1], x1,
            l0g, l0be, l0m, l0v,
            wf + FR_L1X, wf + FR_L1H, l1b, z1,
            c1, h1p[t & 1], h1p[(t + 1) & 1], h1s);
    }
    pool_all<<<512, 256, 0, stream>>>(h1s, dWf, dBf, out);
}